// Round 1
// baseline (696.916 us; speedup 1.0000x reference)
//
#include <hip/hip_runtime.h>

// LinkPredictor: 2-layer GCN encode + edge dot-product decode.
// Dims fixed by the problem: N=50000, E=800000, IN_CH=128, HID=64.
#define INCH 128
#define HIDC 64

__global__ __launch_bounds__(256) void deg_kernel(const int* __restrict__ dst,
                                                  float* __restrict__ deg, int E) {
    int i = blockIdx.x * 256 + threadIdx.x;
    if (i < E) atomicAdd(&deg[dst[i]], 1.0f);
}

__global__ __launch_bounds__(256) void dinv_kernel(float* deg, int N) {
    int i = blockIdx.x * 256 + threadIdx.x;
    if (i < N) deg[i] = rsqrtf(deg[i] + 1.0f);   // +1 for self-loop
}

// h[N,64] = x[N,128] @ W[128,64].  Block = 4 nodes x 64 channels.
__global__ __launch_bounds__(256) void gemm1_kernel(const float* __restrict__ x,
                                                    const float* __restrict__ W,
                                                    float* __restrict__ h, int N) {
    __shared__ float Ws[INCH * HIDC];   // 32 KB
    __shared__ float xs[4][INCH];       // 2 KB
    for (int i = threadIdx.x; i < INCH * HIDC; i += 256) Ws[i] = W[i];
    int node0 = blockIdx.x * 4;
    for (int i = threadIdx.x; i < 4 * INCH; i += 256) {
        int nl = i >> 7, k = i & (INCH - 1);
        int node = node0 + nl;
        xs[nl][k] = (node < N) ? x[(size_t)node * INCH + k] : 0.f;
    }
    __syncthreads();
    int nl = threadIdx.x >> 6, ch = threadIdx.x & 63;
    int node = node0 + nl;
    if (node < N) {
        float acc = 0.f;
        #pragma unroll
        for (int k = 0; k < INCH; ++k) acc = fmaf(xs[nl][k], Ws[k * HIDC + ch], acc);
        h[(size_t)node * HIDC + ch] = acc;
    }
}

// h2[N,64] = relu(agg1[N,64] + b1) @ W2[64,64].  Bias+ReLU fused at load.
__global__ __launch_bounds__(256) void gemm2_kernel(const float* __restrict__ agg1,
                                                    const float* __restrict__ b1,
                                                    const float* __restrict__ W,
                                                    float* __restrict__ h, int N) {
    __shared__ float Ws[HIDC * HIDC];   // 16 KB
    __shared__ float xs[4][HIDC];       // 1 KB
    for (int i = threadIdx.x; i < HIDC * HIDC; i += 256) Ws[i] = W[i];
    int node0 = blockIdx.x * 4;
    for (int i = threadIdx.x; i < 4 * HIDC; i += 256) {
        int nl = i >> 6, k = i & (HIDC - 1);
        int node = node0 + nl;
        xs[nl][k] = (node < N) ? fmaxf(agg1[(size_t)node * HIDC + k] + b1[k], 0.f) : 0.f;
    }
    __syncthreads();
    int nl = threadIdx.x >> 6, ch = threadIdx.x & 63;
    int node = node0 + nl;
    if (node < N) {
        float acc = 0.f;
        #pragma unroll
        for (int k = 0; k < HIDC; ++k) acc = fmaf(xs[nl][k], Ws[k * HIDC + ch], acc);
        h[(size_t)node * HIDC + ch] = acc;
    }
}

// One wave per (edge or self-loop): agg[dst] += h[src] * dinv[src]*dinv[dst].
// wid in [0,E) -> real edge; wid in [E, E+N) -> self-loop (src=dst=wid-E).
__global__ __launch_bounds__(256) void aggregate_kernel(const int* __restrict__ src,
                                                        const int* __restrict__ dst,
                                                        const float* __restrict__ dinv,
                                                        const float* __restrict__ h,
                                                        float* __restrict__ agg,
                                                        int E, int N) {
    long long tid = (long long)blockIdx.x * 256 + threadIdx.x;
    int wid = (int)(tid >> 6);
    int lane = threadIdx.x & 63;
    if (wid >= E + N) return;
    int s, d;
    if (wid < E) { s = src[wid]; d = dst[wid]; }
    else         { s = wid - E;  d = s; }
    float norm = dinv[s] * dinv[d];
    float v = h[(size_t)s * HIDC + lane] * norm;
    atomicAdd(&agg[(size_t)d * HIDC + lane], v);
}

// One wave per edge: out[e] = sum_c (z[src]+b2)[c] * (z[dst]+b2)[c].
__global__ __launch_bounds__(256) void decode_kernel(const int* __restrict__ src,
                                                     const int* __restrict__ dst,
                                                     const float* __restrict__ z,
                                                     const float* __restrict__ b2,
                                                     float* __restrict__ out, int E) {
    long long tid = (long long)blockIdx.x * 256 + threadIdx.x;
    int wid = (int)(tid >> 6);
    int lane = threadIdx.x & 63;
    if (wid >= E) return;
    int s = src[wid], d = dst[wid];
    float zs = z[(size_t)s * HIDC + lane] + b2[lane];
    float zd = z[(size_t)d * HIDC + lane] + b2[lane];
    float p = zs * zd;
    #pragma unroll
    for (int m = 32; m; m >>= 1) p += __shfl_xor(p, m, 64);
    if (lane == 0) out[wid] = p;
}

extern "C" void kernel_launch(void* const* d_in, const int* in_sizes, int n_in,
                              void* d_out, int out_size, void* d_ws, size_t ws_size,
                              hipStream_t stream) {
    const float* x  = (const float*)d_in[0];
    const int*   ei = (const int*)d_in[1];
    const float* W1 = (const float*)d_in[2];
    const float* b1 = (const float*)d_in[3];
    const float* W2 = (const float*)d_in[4];
    const float* b2 = (const float*)d_in[5];
    float* out = (float*)d_out;

    const int hid  = in_sizes[3];            // 64
    const int inch = in_sizes[2] / hid;      // 128
    const int N    = in_sizes[0] / inch;     // 50000
    const int E    = in_sizes[1] / 2;        // 800000
    const int* srcp = ei;
    const int* dstp = ei + E;

    // Workspace layout (floats): [deg|agg1|agg2|h1|h2] — first 3 zeroed in one memset.
    float* ws = (float*)d_ws;
    size_t degPad = ((size_t)N + 63) & ~(size_t)63;
    float* deg  = ws;
    float* agg1 = ws + degPad;
    float* agg2 = agg1 + (size_t)N * HIDC;
    float* h1   = agg2 + (size_t)N * HIDC;
    float* h2   = h1   + (size_t)N * HIDC;

    hipMemsetAsync(ws, 0, (degPad + 2 * (size_t)N * HIDC) * sizeof(float), stream);

    deg_kernel<<<(E + 255) / 256, 256, 0, stream>>>(dstp, deg, E);
    dinv_kernel<<<(N + 255) / 256, 256, 0, stream>>>(deg, N);

    gemm1_kernel<<<(N + 3) / 4, 256, 0, stream>>>(x, W1, h1, N);

    long long waves1 = (long long)E + N;
    long long blocks1 = (waves1 * 64 + 255) / 256;
    aggregate_kernel<<<(int)blocks1, 256, 0, stream>>>(srcp, dstp, deg, h1, agg1, E, N);

    gemm2_kernel<<<(N + 3) / 4, 256, 0, stream>>>(agg1, b1, W2, h2, N);

    aggregate_kernel<<<(int)blocks1, 256, 0, stream>>>(srcp, dstp, deg, h2, agg2, E, N);

    long long blocksD = ((long long)E * 64 + 255) / 256;
    decode_kernel<<<(int)blocksD, 256, 0, stream>>>(srcp, dstp, agg2, b2, out, E);
}

// Round 2
// 591.800 us; speedup vs baseline: 1.1776x; 1.1776x over previous
//
#include <hip/hip_runtime.h>

// LinkPredictor: 2-layer GCN encode + edge dot decode.
// N=50000, E=800000, IN_CH=128, HID=64.
// R2: CSR-by-dst gather aggregation (replaces 54M fp32 atomics -> 0).
#define INCH 128
#define HIDC 64

// --- CSR build ----------------------------------------------------------
__global__ __launch_bounds__(256) void hist_kernel(const int* __restrict__ dst,
                                                   int* __restrict__ count, int E) {
    int i = blockIdx.x * 256 + threadIdx.x;
    if (i < E) atomicAdd(&count[dst[i]], 1);
}

// One block, 1024 threads: exclusive scan of count -> rowptr (N+1) and cursor.
__global__ __launch_bounds__(1024) void scan_kernel(const int* __restrict__ count,
                                                    int* __restrict__ rowptr,
                                                    int* __restrict__ cursor,
                                                    float* __restrict__ dinv, int N) {
    __shared__ int sums[1024];
    int t = threadIdx.x;
    int chunk = (N + 1023) / 1024;
    int beg = t * chunk, end = min(beg + chunk, N);
    int s = 0;
    for (int i = beg; i < end; ++i) s += count[i];
    sums[t] = s;
    __syncthreads();
    for (int off = 1; off < 1024; off <<= 1) {
        int v = (t >= off) ? sums[t - off] : 0;
        __syncthreads();
        sums[t] += v;
        __syncthreads();
    }
    int base = (t > 0) ? sums[t - 1] : 0;
    for (int i = beg; i < end; ++i) {
        rowptr[i] = base;
        cursor[i] = base;
        dinv[i] = rsqrtf((float)count[i] + 1.0f);   // +1 self-loop
        base += count[i];
    }
    if (t == 1023) rowptr[N] = sums[1023];
}

__global__ __launch_bounds__(256) void scatter_kernel(const int* __restrict__ src,
                                                      const int* __restrict__ dst,
                                                      int* __restrict__ cursor,
                                                      int* __restrict__ col, int E) {
    int i = blockIdx.x * 256 + threadIdx.x;
    if (i < E) {
        int d = dst[i];
        int pos = atomicAdd(&cursor[d], 1);
        col[pos] = src[i];
    }
}

// --- dense layers -------------------------------------------------------
// h[N,64] = x[N,128] @ W[128,64].  Block = 4 nodes x 64 channels.
__global__ __launch_bounds__(256) void gemm1_kernel(const float* __restrict__ x,
                                                    const float* __restrict__ W,
                                                    float* __restrict__ h, int N) {
    __shared__ float Ws[INCH * HIDC];
    __shared__ float xs[4][INCH];
    for (int i = threadIdx.x; i < INCH * HIDC; i += 256) Ws[i] = W[i];
    int node0 = blockIdx.x * 4;
    for (int i = threadIdx.x; i < 4 * INCH; i += 256) {
        int nl = i >> 7, k = i & (INCH - 1);
        int node = node0 + nl;
        xs[nl][k] = (node < N) ? x[(size_t)node * INCH + k] : 0.f;
    }
    __syncthreads();
    int nl = threadIdx.x >> 6, ch = threadIdx.x & 63;
    int node = node0 + nl;
    if (node < N) {
        float acc = 0.f;
        #pragma unroll
        for (int k = 0; k < INCH; ++k) acc = fmaf(xs[nl][k], Ws[k * HIDC + ch], acc);
        h[(size_t)node * HIDC + ch] = acc;
    }
}

// h2[N,64] = relu(agg1[N,64] + b1) @ W2[64,64].
__global__ __launch_bounds__(256) void gemm2_kernel(const float* __restrict__ agg1,
                                                    const float* __restrict__ b1,
                                                    const float* __restrict__ W,
                                                    float* __restrict__ h, int N) {
    __shared__ float Ws[HIDC * HIDC];
    __shared__ float xs[4][HIDC];
    for (int i = threadIdx.x; i < HIDC * HIDC; i += 256) Ws[i] = W[i];
    int node0 = blockIdx.x * 4;
    for (int i = threadIdx.x; i < 4 * HIDC; i += 256) {
        int nl = i >> 6, k = i & (HIDC - 1);
        int node = node0 + nl;
        xs[nl][k] = (node < N) ? fmaxf(agg1[(size_t)node * HIDC + k] + b1[k], 0.f) : 0.f;
    }
    __syncthreads();
    int nl = threadIdx.x >> 6, ch = threadIdx.x & 63;
    int node = node0 + nl;
    if (node < N) {
        float acc = 0.f;
        #pragma unroll
        for (int k = 0; k < HIDC; ++k) acc = fmaf(xs[nl][k], Ws[k * HIDC + ch], acc);
        h[(size_t)node * HIDC + ch] = acc;
    }
}

// --- gather-side aggregation -------------------------------------------
// One wave per node: agg[d] = dinv[d] * ( dinv[d]*h[d] + sum_{s in col[d]} dinv[s]*h[s] )
__global__ __launch_bounds__(256) void aggregate_csr_kernel(const int* __restrict__ rowptr,
                                                            const int* __restrict__ col,
                                                            const float* __restrict__ dinv,
                                                            const float* __restrict__ h,
                                                            float* __restrict__ agg, int N) {
    int node = blockIdx.x * 4 + (threadIdx.x >> 6);
    int lane = threadIdx.x & 63;
    if (node >= N) return;
    float dn = dinv[node];
    float acc = h[(size_t)node * HIDC + lane] * dn;   // self-loop (x dn again at end)
    int j = rowptr[node], end = rowptr[node + 1];
    // unroll by 2 for load pipelining
    for (; j + 1 < end; j += 2) {
        int s0 = col[j], s1 = col[j + 1];
        float w0 = dinv[s0], w1 = dinv[s1];
        float v0 = h[(size_t)s0 * HIDC + lane];
        float v1 = h[(size_t)s1 * HIDC + lane];
        acc = fmaf(v0, w0, acc);
        acc = fmaf(v1, w1, acc);
    }
    if (j < end) {
        int s0 = col[j];
        acc = fmaf(h[(size_t)s0 * HIDC + lane], dinv[s0], acc);
    }
    agg[(size_t)node * HIDC + lane] = acc * dn;
}

// --- decode -------------------------------------------------------------
__global__ __launch_bounds__(256) void decode_kernel(const int* __restrict__ src,
                                                     const int* __restrict__ dst,
                                                     const float* __restrict__ z,
                                                     const float* __restrict__ b2,
                                                     float* __restrict__ out, int E) {
    long long tid = (long long)blockIdx.x * 256 + threadIdx.x;
    int wid = (int)(tid >> 6);
    int lane = threadIdx.x & 63;
    if (wid >= E) return;
    int s = src[wid], d = dst[wid];
    float zs = z[(size_t)s * HIDC + lane] + b2[lane];
    float zd = z[(size_t)d * HIDC + lane] + b2[lane];
    float p = zs * zd;
    #pragma unroll
    for (int m = 32; m; m >>= 1) p += __shfl_xor(p, m, 64);
    if (lane == 0) out[wid] = p;
}

extern "C" void kernel_launch(void* const* d_in, const int* in_sizes, int n_in,
                              void* d_out, int out_size, void* d_ws, size_t ws_size,
                              hipStream_t stream) {
    const float* x  = (const float*)d_in[0];
    const int*   ei = (const int*)d_in[1];
    const float* W1 = (const float*)d_in[2];
    const float* b1 = (const float*)d_in[3];
    const float* W2 = (const float*)d_in[4];
    const float* b2 = (const float*)d_in[5];
    float* out = (float*)d_out;

    const int hid  = in_sizes[3];            // 64
    const int inch = in_sizes[2] / hid;      // 128
    const int N    = in_sizes[0] / inch;     // 50000
    const int E    = in_sizes[1] / 2;        // 800000
    const int* srcp = ei;
    const int* dstp = ei + E;

    // Workspace (4-byte units):
    // [count N | rowptr N+1 | cursor N | dinv N | col E | bufA N*64 | bufB N*64]
    char* ws = (char*)d_ws;
    size_t Np = ((size_t)N + 64) & ~(size_t)63;   // padded, covers N+1
    int*   count  = (int*)ws;
    int*   rowptr = count + Np;
    int*   cursor = rowptr + Np;
    float* dinv   = (float*)(cursor + Np);
    int*   col    = (int*)(dinv + Np);
    size_t Ep = ((size_t)E + 63) & ~(size_t)63;
    float* bufA   = (float*)(col + Ep);
    float* bufB   = bufA + (size_t)N * HIDC;

    // zero only the histogram
    hipMemsetAsync(count, 0, Np * sizeof(int), stream);

    hist_kernel<<<(E + 255) / 256, 256, 0, stream>>>(dstp, count, E);
    scan_kernel<<<1, 1024, 0, stream>>>(count, rowptr, cursor, dinv, N);
    scatter_kernel<<<(E + 255) / 256, 256, 0, stream>>>(srcp, dstp, cursor, col, E);

    gemm1_kernel<<<(N + 3) / 4, 256, 0, stream>>>(x, W1, bufA, N);                 // h1 = bufA
    aggregate_csr_kernel<<<(N + 3) / 4, 256, 0, stream>>>(rowptr, col, dinv, bufA, bufB, N);  // agg1 = bufB
    gemm2_kernel<<<(N + 3) / 4, 256, 0, stream>>>(bufB, b1, W2, bufA, N);          // h2 = bufA
    aggregate_csr_kernel<<<(N + 3) / 4, 256, 0, stream>>>(rowptr, col, dinv, bufA, bufB, N);  // z = bufB

    long long blocksD = ((long long)E * 64 + 255) / 256;
    decode_kernel<<<(int)blocksD, 256, 0, stream>>>(srcp, dstp, bufB, b2, out, E);
}

// Round 3
// 385.973 us; speedup vs baseline: 1.8056x; 1.5333x over previous
//
#include <hip/hip_runtime.h>

// LinkPredictor: 2-layer GCN encode + edge dot decode.
// N=50000, E=800000, IN_CH=128, HID=64.
// R3: parallel 3-phase scan (was 134us single-block), grid-stride gemms,
//     float4 quarter-wave decode.
#define INCH 128
#define HIDC 64

// --- CSR build ----------------------------------------------------------
__global__ __launch_bounds__(256) void hist_kernel(const int* __restrict__ dst,
                                                   int* __restrict__ count, int E) {
    int i = blockIdx.x * 256 + threadIdx.x;
    if (i < E) atomicAdd(&count[dst[i]], 1);
}

// Phase A: block b scans 1024 counts -> local exclusive scan into rowptr,
// block total into bsums[b].
__global__ __launch_bounds__(256) void scanA_kernel(const int* __restrict__ count,
                                                    int* __restrict__ rowptr,
                                                    int* __restrict__ bsums, int N) {
    int t = threadIdx.x;
    int base = blockIdx.x * 1024 + t * 4;
    int c0 = (base + 0 < N) ? count[base + 0] : 0;
    int c1 = (base + 1 < N) ? count[base + 1] : 0;
    int c2 = (base + 2 < N) ? count[base + 2] : 0;
    int c3 = (base + 3 < N) ? count[base + 3] : 0;
    int tsum = c0 + c1 + c2 + c3;
    int lane = t & 63, wid = t >> 6;
    int incl = tsum;
    #pragma unroll
    for (int off = 1; off < 64; off <<= 1) {
        int u = __shfl_up(incl, off, 64);
        if (lane >= off) incl += u;
    }
    __shared__ int waveSums[4];
    if (lane == 63) waveSums[wid] = incl;
    __syncthreads();
    int waveOff = 0;
    for (int w = 0; w < wid; ++w) waveOff += waveSums[w];
    int texcl = waveOff + incl - tsum;
    if (base + 0 < N) rowptr[base + 0] = texcl;
    if (base + 1 < N) rowptr[base + 1] = texcl + c0;
    if (base + 2 < N) rowptr[base + 2] = texcl + c0 + c1;
    if (base + 3 < N) rowptr[base + 3] = texcl + c0 + c1 + c2;
    if (t == 255) bsums[blockIdx.x] = waveOff + incl;
}

// Phase B: one wave exclusive-scans bsums (nb <= a few hundred).
__global__ __launch_bounds__(64) void scanB_kernel(int* __restrict__ bsums, int nb) {
    int lane = threadIdx.x;
    int carry = 0;
    for (int base = 0; base < nb; base += 64) {
        int i = base + lane;
        int v = (i < nb) ? bsums[i] : 0;
        int incl = v;
        #pragma unroll
        for (int off = 1; off < 64; off <<= 1) {
            int u = __shfl_up(incl, off, 64);
            if (lane >= off) incl += u;
        }
        if (i < nb) bsums[i] = carry + incl - v;
        carry += __shfl(incl, 63, 64);
    }
}

// Phase C: add block offsets; emit rowptr, cursor, dinv.
__global__ __launch_bounds__(256) void scanC_kernel(const int* __restrict__ count,
                                                    const int* __restrict__ bsums,
                                                    int* __restrict__ rowptr,
                                                    int* __restrict__ cursor,
                                                    float* __restrict__ dinv,
                                                    int N, int E) {
    int i = blockIdx.x * 256 + threadIdx.x;
    if (i < N) {
        int r = rowptr[i] + bsums[i >> 10];
        rowptr[i] = r;
        cursor[i] = r;
        dinv[i] = rsqrtf((float)count[i] + 1.0f);   // +1 self-loop
    }
    if (i == 0) rowptr[N] = E;
}

__global__ __launch_bounds__(256) void scatter_kernel(const int* __restrict__ src,
                                                      const int* __restrict__ dst,
                                                      int* __restrict__ cursor,
                                                      int* __restrict__ col, int E) {
    int i = blockIdx.x * 256 + threadIdx.x;
    if (i < E) {
        int d = dst[i];
        int pos = atomicAdd(&cursor[d], 1);
        col[pos] = src[i];
    }
}

// --- dense layers (grid-stride: W loaded to LDS once per block) ---------
__global__ __launch_bounds__(256) void gemm1_kernel(const float* __restrict__ x,
                                                    const float* __restrict__ W,
                                                    float* __restrict__ h, int N) {
    __shared__ float Ws[INCH * HIDC];
    __shared__ float xs[4][INCH];
    for (int i = threadIdx.x; i < INCH * HIDC; i += 256) Ws[i] = W[i];
    int nl = threadIdx.x >> 6, ch = threadIdx.x & 63;
    int nTiles = (N + 3) / 4;
    for (int tile = blockIdx.x; tile < nTiles; tile += gridDim.x) {
        int node0 = tile * 4;
        __syncthreads();
        for (int i = threadIdx.x; i < 4 * INCH; i += 256) {
            int l = i >> 7, k = i & (INCH - 1);
            int node = node0 + l;
            xs[l][k] = (node < N) ? x[(size_t)node * INCH + k] : 0.f;
        }
        __syncthreads();
        int node = node0 + nl;
        if (node < N) {
            float acc = 0.f;
            #pragma unroll
            for (int k = 0; k < INCH; ++k) acc = fmaf(xs[nl][k], Ws[k * HIDC + ch], acc);
            h[(size_t)node * HIDC + ch] = acc;
        }
    }
}

__global__ __launch_bounds__(256) void gemm2_kernel(const float* __restrict__ agg1,
                                                    const float* __restrict__ b1,
                                                    const float* __restrict__ W,
                                                    float* __restrict__ h, int N) {
    __shared__ float Ws[HIDC * HIDC];
    __shared__ float xs[4][HIDC];
    for (int i = threadIdx.x; i < HIDC * HIDC; i += 256) Ws[i] = W[i];
    int nl = threadIdx.x >> 6, ch = threadIdx.x & 63;
    int nTiles = (N + 3) / 4;
    for (int tile = blockIdx.x; tile < nTiles; tile += gridDim.x) {
        int node0 = tile * 4;
        __syncthreads();
        for (int i = threadIdx.x; i < 4 * HIDC; i += 256) {
            int l = i >> 6, k = i & (HIDC - 1);
            int node = node0 + l;
            xs[l][k] = (node < N) ? fmaxf(agg1[(size_t)node * HIDC + k] + b1[k], 0.f) : 0.f;
        }
        __syncthreads();
        int node = node0 + nl;
        if (node < N) {
            float acc = 0.f;
            #pragma unroll
            for (int k = 0; k < HIDC; ++k) acc = fmaf(xs[nl][k], Ws[k * HIDC + ch], acc);
            h[(size_t)node * HIDC + ch] = acc;
        }
    }
}

// --- gather-side aggregation -------------------------------------------
__global__ __launch_bounds__(256) void aggregate_csr_kernel(const int* __restrict__ rowptr,
                                                            const int* __restrict__ col,
                                                            const float* __restrict__ dinv,
                                                            const float* __restrict__ h,
                                                            float* __restrict__ agg, int N) {
    int node = blockIdx.x * 4 + (threadIdx.x >> 6);
    int lane = threadIdx.x & 63;
    if (node >= N) return;
    float dn = dinv[node];
    float acc = h[(size_t)node * HIDC + lane] * dn;   // self-loop
    int j = rowptr[node], end = rowptr[node + 1];
    for (; j + 1 < end; j += 2) {
        int s0 = col[j], s1 = col[j + 1];
        float w0 = dinv[s0], w1 = dinv[s1];
        float v0 = h[(size_t)s0 * HIDC + lane];
        float v1 = h[(size_t)s1 * HIDC + lane];
        acc = fmaf(v0, w0, acc);
        acc = fmaf(v1, w1, acc);
    }
    if (j < end) {
        int s0 = col[j];
        acc = fmaf(h[(size_t)s0 * HIDC + lane], dinv[s0], acc);
    }
    agg[(size_t)node * HIDC + lane] = acc * dn;
}

// --- decode: 16 lanes per edge, float4 ----------------------------------
__global__ __launch_bounds__(256) void decode_kernel(const int* __restrict__ src,
                                                     const int* __restrict__ dst,
                                                     const float* __restrict__ z,
                                                     const float* __restrict__ b2,
                                                     float* __restrict__ out, int E) {
    long long tid = (long long)blockIdx.x * 256 + threadIdx.x;
    int e = (int)(tid >> 4);            // 16 lanes per edge
    int q = threadIdx.x & 15;
    if (e >= E) return;
    int s = src[e], d = dst[e];
    const float4* z4 = (const float4*)z;
    const float4* b4 = (const float4*)b2;
    float4 bb = b4[q];
    float4 zs = z4[(size_t)s * 16 + q];
    float4 zd = z4[(size_t)d * 16 + q];
    float p = (zs.x + bb.x) * (zd.x + bb.x)
            + (zs.y + bb.y) * (zd.y + bb.y)
            + (zs.z + bb.z) * (zd.z + bb.z)
            + (zs.w + bb.w) * (zd.w + bb.w);
    #pragma unroll
    for (int m = 8; m; m >>= 1) p += __shfl_xor(p, m, 64);
    if (q == 0) out[e] = p;
}

extern "C" void kernel_launch(void* const* d_in, const int* in_sizes, int n_in,
                              void* d_out, int out_size, void* d_ws, size_t ws_size,
                              hipStream_t stream) {
    const float* x  = (const float*)d_in[0];
    const int*   ei = (const int*)d_in[1];
    const float* W1 = (const float*)d_in[2];
    const float* b1 = (const float*)d_in[3];
    const float* W2 = (const float*)d_in[4];
    const float* b2 = (const float*)d_in[5];
    float* out = (float*)d_out;

    const int hid  = in_sizes[3];            // 64
    const int inch = in_sizes[2] / hid;      // 128
    const int N    = in_sizes[0] / inch;     // 50000
    const int E    = in_sizes[1] / 2;        // 800000
    const int* srcp = ei;
    const int* dstp = ei + E;

    // Workspace (ints/floats, all 256B-aligned regions):
    // [count Np | rowptr Np | cursor Np | dinv Np | bsums 64+ | col Ep | bufA | bufB]
    char* ws = (char*)d_ws;
    size_t Np = ((size_t)N + 64) & ~(size_t)63;
    int nScanBlocks = (N + 1023) / 1024;
    size_t Bp = ((size_t)nScanBlocks + 63) & ~(size_t)63;
    int*   count  = (int*)ws;
    int*   rowptr = count + Np;
    int*   cursor = rowptr + Np;
    float* dinv   = (float*)(cursor + Np);
    int*   bsums  = (int*)(dinv + Np);
    int*   col    = bsums + Bp;
    size_t Ep = ((size_t)E + 63) & ~(size_t)63;
    float* bufA   = (float*)(col + Ep);
    float* bufB   = bufA + (size_t)N * HIDC;

    hipMemsetAsync(count, 0, Np * sizeof(int), stream);

    hist_kernel<<<(E + 255) / 256, 256, 0, stream>>>(dstp, count, E);
    scanA_kernel<<<nScanBlocks, 256, 0, stream>>>(count, rowptr, bsums, N);
    scanB_kernel<<<1, 64, 0, stream>>>(bsums, nScanBlocks);
    scanC_kernel<<<(N + 255) / 256, 256, 0, stream>>>(count, bsums, rowptr, cursor, dinv, N, E);
    scatter_kernel<<<(E + 255) / 256, 256, 0, stream>>>(srcp, dstp, cursor, col, E);

    gemm1_kernel<<<1280, 256, 0, stream>>>(x, W1, bufA, N);                        // h1 = bufA
    aggregate_csr_kernel<<<(N + 3) / 4, 256, 0, stream>>>(rowptr, col, dinv, bufA, bufB, N);
    gemm2_kernel<<<1280, 256, 0, stream>>>(bufB, b1, W2, bufA, N);                 // h2 = bufA
    aggregate_csr_kernel<<<(N + 3) / 4, 256, 0, stream>>>(rowptr, col, dinv, bufA, bufB, N);

    long long blocksD = ((long long)E * 16 + 255) / 256;
    decode_kernel<<<(int)blocksD, 256, 0, stream>>>(srcp, dstp, bufB, b2, out, E);
}

// Round 4
// 319.863 us; speedup vs baseline: 2.1788x; 1.2067x over previous
//
#include <hip/hip_runtime.h>

// LinkPredictor: 2-layer GCN encode + edge dot decode.
// N=50000, E=800000, IN_CH=128, HID=64.
// R4: register/SGPR gemms (no LDS; W via uniform s_load), atomic-free
//     scatter with uint16 rank/col.
#define INCH 128
#define HIDC 64

// --- CSR build ----------------------------------------------------------
// hist also assigns each edge its rank within its dst row.
__global__ __launch_bounds__(256) void hist_kernel(const int* __restrict__ dst,
                                                   int* __restrict__ count,
                                                   unsigned short* __restrict__ rank, int E) {
    int i = blockIdx.x * 256 + threadIdx.x;
    if (i < E) rank[i] = (unsigned short)atomicAdd(&count[dst[i]], 1);
}

// Phase A: block scans 1024 counts -> local exclusive scan into rowptr + block sum.
__global__ __launch_bounds__(256) void scanA_kernel(const int* __restrict__ count,
                                                    int* __restrict__ rowptr,
                                                    int* __restrict__ bsums, int N) {
    int t = threadIdx.x;
    int base = blockIdx.x * 1024 + t * 4;
    int c0 = (base + 0 < N) ? count[base + 0] : 0;
    int c1 = (base + 1 < N) ? count[base + 1] : 0;
    int c2 = (base + 2 < N) ? count[base + 2] : 0;
    int c3 = (base + 3 < N) ? count[base + 3] : 0;
    int tsum = c0 + c1 + c2 + c3;
    int lane = t & 63, wid = t >> 6;
    int incl = tsum;
    #pragma unroll
    for (int off = 1; off < 64; off <<= 1) {
        int u = __shfl_up(incl, off, 64);
        if (lane >= off) incl += u;
    }
    __shared__ int waveSums[4];
    if (lane == 63) waveSums[wid] = incl;
    __syncthreads();
    int waveOff = 0;
    for (int w = 0; w < wid; ++w) waveOff += waveSums[w];
    int texcl = waveOff + incl - tsum;
    if (base + 0 < N) rowptr[base + 0] = texcl;
    if (base + 1 < N) rowptr[base + 1] = texcl + c0;
    if (base + 2 < N) rowptr[base + 2] = texcl + c0 + c1;
    if (base + 3 < N) rowptr[base + 3] = texcl + c0 + c1 + c2;
    if (t == 255) bsums[blockIdx.x] = waveOff + incl;
}

__global__ __launch_bounds__(64) void scanB_kernel(int* __restrict__ bsums, int nb) {
    int lane = threadIdx.x;
    int carry = 0;
    for (int base = 0; base < nb; base += 64) {
        int i = base + lane;
        int v = (i < nb) ? bsums[i] : 0;
        int incl = v;
        #pragma unroll
        for (int off = 1; off < 64; off <<= 1) {
            int u = __shfl_up(incl, off, 64);
            if (lane >= off) incl += u;
        }
        if (i < nb) bsums[i] = carry + incl - v;
        carry += __shfl(incl, 63, 64);
    }
}

__global__ __launch_bounds__(256) void scanC_kernel(const int* __restrict__ count,
                                                    const int* __restrict__ bsums,
                                                    int* __restrict__ rowptr,
                                                    float* __restrict__ dinv,
                                                    int N, int E) {
    int i = blockIdx.x * 256 + threadIdx.x;
    if (i < N) {
        rowptr[i] += bsums[i >> 10];
        dinv[i] = rsqrtf((float)count[i] + 1.0f);   // +1 self-loop
    }
    if (i == 0) rowptr[N] = E;
}

// Atomic-free scatter: position = rowptr[dst] + rank.
__global__ __launch_bounds__(256) void scatter_kernel(const int* __restrict__ src,
                                                      const int* __restrict__ dst,
                                                      const int* __restrict__ rowptr,
                                                      const unsigned short* __restrict__ rank,
                                                      unsigned short* __restrict__ col, int E) {
    int i = blockIdx.x * 256 + threadIdx.x;
    if (i < E) {
        int d = dst[i];
        col[rowptr[d] + (int)rank[i]] = (unsigned short)src[i];
    }
}

// --- dense layers: thread-per-node, W via wave-uniform s_load -----------
// Block parity selects the 32-channel half so W indices stay uniform.
__global__ __launch_bounds__(256) void gemm1_kernel(const float* __restrict__ x,
                                                    const float* __restrict__ W,
                                                    float* __restrict__ h, int N) {
    int node = (blockIdx.x >> 1) * 256 + threadIdx.x;
    int ch0 = (blockIdx.x & 1) * 32;
    if (node >= N) return;
    const float4* xr = (const float4*)(x + (size_t)node * INCH);
    float acc[32];
    #pragma unroll
    for (int c = 0; c < 32; ++c) acc[c] = 0.f;
    for (int kc = 0; kc < INCH / 4; ++kc) {
        float4 xk = xr[kc];
        const float* wr = W + (kc * 4) * HIDC + ch0;
        #pragma unroll
        for (int ch = 0; ch < 32; ++ch) acc[ch] = fmaf(xk.x, wr[ch], acc[ch]);
        #pragma unroll
        for (int ch = 0; ch < 32; ++ch) acc[ch] = fmaf(xk.y, wr[HIDC + ch], acc[ch]);
        #pragma unroll
        for (int ch = 0; ch < 32; ++ch) acc[ch] = fmaf(xk.z, wr[2 * HIDC + ch], acc[ch]);
        #pragma unroll
        for (int ch = 0; ch < 32; ++ch) acc[ch] = fmaf(xk.w, wr[3 * HIDC + ch], acc[ch]);
    }
    float4* hr = (float4*)(h + (size_t)node * HIDC + ch0);
    #pragma unroll
    for (int c4 = 0; c4 < 8; ++c4)
        hr[c4] = make_float4(acc[4 * c4], acc[4 * c4 + 1], acc[4 * c4 + 2], acc[4 * c4 + 3]);
}

// h2[:,ch0:ch0+32] = relu(agg1 + b1) @ W2 ; bias+ReLU fused at load.
__global__ __launch_bounds__(256) void gemm2_kernel(const float* __restrict__ agg1,
                                                    const float* __restrict__ b1,
                                                    const float* __restrict__ W,
                                                    float* __restrict__ h, int N) {
    int node = (blockIdx.x >> 1) * 256 + threadIdx.x;
    int ch0 = (blockIdx.x & 1) * 32;
    if (node >= N) return;
    const float4* ar = (const float4*)(agg1 + (size_t)node * HIDC);
    const float4* b4 = (const float4*)b1;
    float acc[32];
    #pragma unroll
    for (int c = 0; c < 32; ++c) acc[c] = 0.f;
    for (int kc = 0; kc < HIDC / 4; ++kc) {
        float4 ak = ar[kc];
        float4 bk = b4[kc];                       // uniform -> s_load
        float v0 = fmaxf(ak.x + bk.x, 0.f);
        float v1 = fmaxf(ak.y + bk.y, 0.f);
        float v2 = fmaxf(ak.z + bk.z, 0.f);
        float v3 = fmaxf(ak.w + bk.w, 0.f);
        const float* wr = W + (kc * 4) * HIDC + ch0;
        #pragma unroll
        for (int ch = 0; ch < 32; ++ch) acc[ch] = fmaf(v0, wr[ch], acc[ch]);
        #pragma unroll
        for (int ch = 0; ch < 32; ++ch) acc[ch] = fmaf(v1, wr[HIDC + ch], acc[ch]);
        #pragma unroll
        for (int ch = 0; ch < 32; ++ch) acc[ch] = fmaf(v2, wr[2 * HIDC + ch], acc[ch]);
        #pragma unroll
        for (int ch = 0; ch < 32; ++ch) acc[ch] = fmaf(v3, wr[3 * HIDC + ch], acc[ch]);
    }
    float4* hr = (float4*)(h + (size_t)node * HIDC + ch0);
    #pragma unroll
    for (int c4 = 0; c4 < 8; ++c4)
        hr[c4] = make_float4(acc[4 * c4], acc[4 * c4 + 1], acc[4 * c4 + 2], acc[4 * c4 + 3]);
}

// --- gather-side aggregation -------------------------------------------
__global__ __launch_bounds__(256) void aggregate_csr_kernel(const int* __restrict__ rowptr,
                                                            const unsigned short* __restrict__ col,
                                                            const float* __restrict__ dinv,
                                                            const float* __restrict__ h,
                                                            float* __restrict__ agg, int N) {
    int node = blockIdx.x * 4 + (threadIdx.x >> 6);
    int lane = threadIdx.x & 63;
    if (node >= N) return;
    float dn = dinv[node];
    float acc = h[(size_t)node * HIDC + lane] * dn;   // self-loop
    int j = rowptr[node], end = rowptr[node + 1];
    for (; j + 1 < end; j += 2) {
        int s0 = col[j], s1 = col[j + 1];
        float w0 = dinv[s0], w1 = dinv[s1];
        float v0 = h[(size_t)s0 * HIDC + lane];
        float v1 = h[(size_t)s1 * HIDC + lane];
        acc = fmaf(v0, w0, acc);
        acc = fmaf(v1, w1, acc);
    }
    if (j < end) {
        int s0 = col[j];
        acc = fmaf(h[(size_t)s0 * HIDC + lane], dinv[s0], acc);
    }
    agg[(size_t)node * HIDC + lane] = acc * dn;
}

// --- decode: 16 lanes per edge, float4 ----------------------------------
__global__ __launch_bounds__(256) void decode_kernel(const int* __restrict__ src,
                                                     const int* __restrict__ dst,
                                                     const float* __restrict__ z,
                                                     const float* __restrict__ b2,
                                                     float* __restrict__ out, int E) {
    long long tid = (long long)blockIdx.x * 256 + threadIdx.x;
    int e = (int)(tid >> 4);
    int q = threadIdx.x & 15;
    if (e >= E) return;
    int s = src[e], d = dst[e];
    const float4* z4 = (const float4*)z;
    const float4* b4 = (const float4*)b2;
    float4 bb = b4[q];
    float4 zs = z4[(size_t)s * 16 + q];
    float4 zd = z4[(size_t)d * 16 + q];
    float p = (zs.x + bb.x) * (zd.x + bb.x)
            + (zs.y + bb.y) * (zd.y + bb.y)
            + (zs.z + bb.z) * (zd.z + bb.z)
            + (zs.w + bb.w) * (zd.w + bb.w);
    #pragma unroll
    for (int m = 8; m; m >>= 1) p += __shfl_xor(p, m, 64);
    if (q == 0) out[e] = p;
}

extern "C" void kernel_launch(void* const* d_in, const int* in_sizes, int n_in,
                              void* d_out, int out_size, void* d_ws, size_t ws_size,
                              hipStream_t stream) {
    const float* x  = (const float*)d_in[0];
    const int*   ei = (const int*)d_in[1];
    const float* W1 = (const float*)d_in[2];
    const float* b1 = (const float*)d_in[3];
    const float* W2 = (const float*)d_in[4];
    const float* b2 = (const float*)d_in[5];
    float* out = (float*)d_out;

    const int hid  = in_sizes[3];            // 64
    const int inch = in_sizes[2] / hid;      // 128
    const int N    = in_sizes[0] / inch;     // 50000
    const int E    = in_sizes[1] / 2;        // 800000
    const int* srcp = ei;
    const int* dstp = ei + E;
    int nScanBlocks = (N + 1023) / 1024;

    // Workspace: 256B-aligned regions.
    char* p = (char*)d_ws;
    auto alloc = [&](size_t bytes) { char* r = p; p += (bytes + 255) & ~(size_t)255; return r; };
    int*            count  = (int*)alloc((size_t)(N + 1) * 4);
    int*            rowptr = (int*)alloc((size_t)(N + 1) * 4);
    float*          dinv   = (float*)alloc((size_t)N * 4);
    int*            bsums  = (int*)alloc((size_t)nScanBlocks * 4);
    unsigned short* rank   = (unsigned short*)alloc((size_t)E * 2);
    unsigned short* col    = (unsigned short*)alloc((size_t)E * 2);
    float*          bufA   = (float*)alloc((size_t)N * HIDC * 4);
    float*          bufB   = (float*)alloc((size_t)N * HIDC * 4);

    hipMemsetAsync(count, 0, (size_t)N * 4, stream);

    hist_kernel<<<(E + 255) / 256, 256, 0, stream>>>(dstp, count, rank, E);
    scanA_kernel<<<nScanBlocks, 256, 0, stream>>>(count, rowptr, bsums, N);
    scanB_kernel<<<1, 64, 0, stream>>>(bsums, nScanBlocks);
    scanC_kernel<<<(N + 255) / 256, 256, 0, stream>>>(count, bsums, rowptr, dinv, N, E);
    scatter_kernel<<<(E + 255) / 256, 256, 0, stream>>>(srcp, dstp, rowptr, rank, col, E);

    int gemmGrid = 2 * ((N + 255) / 256);
    gemm1_kernel<<<gemmGrid, 256, 0, stream>>>(x, W1, bufA, N);                    // h1 = bufA
    aggregate_csr_kernel<<<(N + 3) / 4, 256, 0, stream>>>(rowptr, col, dinv, bufA, bufB, N);
    gemm2_kernel<<<gemmGrid, 256, 0, stream>>>(bufB, b1, W2, bufA, N);             // h2 = bufA
    aggregate_csr_kernel<<<(N + 3) / 4, 256, 0, stream>>>(rowptr, col, dinv, bufA, bufB, N);

    long long blocksD = ((long long)E * 16 + 255) / 256;
    decode_kernel<<<(int)blocksD, 256, 0, stream>>>(srcp, dstp, bufB, b2, out, E);
}

// Round 5
// 279.698 us; speedup vs baseline: 2.4917x; 1.1436x over previous
//
#include <hip/hip_runtime.h>

// LinkPredictor: 2-layer GCN encode + edge dot decode.
// N=50000, E=800000, IN_CH=128, HID=64.
// R5: pre-scaled h tables (dinv folded at gemm output -> 2-deep gather chain),
//     16-wide clamped gather batches in aggregate for MLP.
#define INCH 128
#define HIDC 64

// --- CSR build ----------------------------------------------------------
__global__ __launch_bounds__(256) void hist_kernel(const int* __restrict__ dst,
                                                   int* __restrict__ count,
                                                   unsigned short* __restrict__ rank, int E) {
    int i = blockIdx.x * 256 + threadIdx.x;
    if (i < E) rank[i] = (unsigned short)atomicAdd(&count[dst[i]], 1);
}

__global__ __launch_bounds__(256) void scanA_kernel(const int* __restrict__ count,
                                                    int* __restrict__ rowptr,
                                                    int* __restrict__ bsums, int N) {
    int t = threadIdx.x;
    int base = blockIdx.x * 1024 + t * 4;
    int c0 = (base + 0 < N) ? count[base + 0] : 0;
    int c1 = (base + 1 < N) ? count[base + 1] : 0;
    int c2 = (base + 2 < N) ? count[base + 2] : 0;
    int c3 = (base + 3 < N) ? count[base + 3] : 0;
    int tsum = c0 + c1 + c2 + c3;
    int lane = t & 63, wid = t >> 6;
    int incl = tsum;
    #pragma unroll
    for (int off = 1; off < 64; off <<= 1) {
        int u = __shfl_up(incl, off, 64);
        if (lane >= off) incl += u;
    }
    __shared__ int waveSums[4];
    if (lane == 63) waveSums[wid] = incl;
    __syncthreads();
    int waveOff = 0;
    for (int w = 0; w < wid; ++w) waveOff += waveSums[w];
    int texcl = waveOff + incl - tsum;
    if (base + 0 < N) rowptr[base + 0] = texcl;
    if (base + 1 < N) rowptr[base + 1] = texcl + c0;
    if (base + 2 < N) rowptr[base + 2] = texcl + c0 + c1;
    if (base + 3 < N) rowptr[base + 3] = texcl + c0 + c1 + c2;
    if (t == 255) bsums[blockIdx.x] = waveOff + incl;
}

__global__ __launch_bounds__(64) void scanB_kernel(int* __restrict__ bsums, int nb) {
    int lane = threadIdx.x;
    int carry = 0;
    for (int base = 0; base < nb; base += 64) {
        int i = base + lane;
        int v = (i < nb) ? bsums[i] : 0;
        int incl = v;
        #pragma unroll
        for (int off = 1; off < 64; off <<= 1) {
            int u = __shfl_up(incl, off, 64);
            if (lane >= off) incl += u;
        }
        if (i < nb) bsums[i] = carry + incl - v;
        carry += __shfl(incl, 63, 64);
    }
}

__global__ __launch_bounds__(256) void scanC_kernel(const int* __restrict__ count,
                                                    const int* __restrict__ bsums,
                                                    int* __restrict__ rowptr,
                                                    float* __restrict__ dinv,
                                                    int N, int E) {
    int i = blockIdx.x * 256 + threadIdx.x;
    if (i < N) {
        rowptr[i] += bsums[i >> 10];
        dinv[i] = rsqrtf((float)count[i] + 1.0f);   // +1 self-loop
    }
    if (i == 0) rowptr[N] = E;
}

__global__ __launch_bounds__(256) void scatter_kernel(const int* __restrict__ src,
                                                      const int* __restrict__ dst,
                                                      const int* __restrict__ rowptr,
                                                      const unsigned short* __restrict__ rank,
                                                      unsigned short* __restrict__ col, int E) {
    int i = blockIdx.x * 256 + threadIdx.x;
    if (i < E) {
        int d = dst[i];
        col[rowptr[d] + (int)rank[i]] = (unsigned short)src[i];
    }
}

// --- dense layers: thread-per-node, W via wave-uniform s_load -----------
// Output pre-scaled by dinv[node] so aggregation needs no per-edge weights.
__global__ __launch_bounds__(256) void gemm1_kernel(const float* __restrict__ x,
                                                    const float* __restrict__ W,
                                                    const float* __restrict__ dinv,
                                                    float* __restrict__ hs, int N) {
    int node = (blockIdx.x >> 1) * 256 + threadIdx.x;
    int ch0 = (blockIdx.x & 1) * 32;
    if (node >= N) return;
    const float4* xr = (const float4*)(x + (size_t)node * INCH);
    float acc[32];
    #pragma unroll
    for (int c = 0; c < 32; ++c) acc[c] = 0.f;
    for (int kc = 0; kc < INCH / 4; ++kc) {
        float4 xk = xr[kc];
        const float* wr = W + (kc * 4) * HIDC + ch0;
        #pragma unroll
        for (int ch = 0; ch < 32; ++ch) acc[ch] = fmaf(xk.x, wr[ch], acc[ch]);
        #pragma unroll
        for (int ch = 0; ch < 32; ++ch) acc[ch] = fmaf(xk.y, wr[HIDC + ch], acc[ch]);
        #pragma unroll
        for (int ch = 0; ch < 32; ++ch) acc[ch] = fmaf(xk.z, wr[2 * HIDC + ch], acc[ch]);
        #pragma unroll
        for (int ch = 0; ch < 32; ++ch) acc[ch] = fmaf(xk.w, wr[3 * HIDC + ch], acc[ch]);
    }
    float dn = dinv[node];
    float4* hr = (float4*)(hs + (size_t)node * HIDC + ch0);
    #pragma unroll
    for (int c4 = 0; c4 < 8; ++c4)
        hr[c4] = make_float4(dn * acc[4 * c4], dn * acc[4 * c4 + 1],
                             dn * acc[4 * c4 + 2], dn * acc[4 * c4 + 3]);
}

__global__ __launch_bounds__(256) void gemm2_kernel(const float* __restrict__ agg1,
                                                    const float* __restrict__ b1,
                                                    const float* __restrict__ W,
                                                    const float* __restrict__ dinv,
                                                    float* __restrict__ hs, int N) {
    int node = (blockIdx.x >> 1) * 256 + threadIdx.x;
    int ch0 = (blockIdx.x & 1) * 32;
    if (node >= N) return;
    const float4* ar = (const float4*)(agg1 + (size_t)node * HIDC);
    const float4* b4 = (const float4*)b1;
    float acc[32];
    #pragma unroll
    for (int c = 0; c < 32; ++c) acc[c] = 0.f;
    for (int kc = 0; kc < HIDC / 4; ++kc) {
        float4 ak = ar[kc];
        float4 bk = b4[kc];
        float v0 = fmaxf(ak.x + bk.x, 0.f);
        float v1 = fmaxf(ak.y + bk.y, 0.f);
        float v2 = fmaxf(ak.z + bk.z, 0.f);
        float v3 = fmaxf(ak.w + bk.w, 0.f);
        const float* wr = W + (kc * 4) * HIDC + ch0;
        #pragma unroll
        for (int ch = 0; ch < 32; ++ch) acc[ch] = fmaf(v0, wr[ch], acc[ch]);
        #pragma unroll
        for (int ch = 0; ch < 32; ++ch) acc[ch] = fmaf(v1, wr[HIDC + ch], acc[ch]);
        #pragma unroll
        for (int ch = 0; ch < 32; ++ch) acc[ch] = fmaf(v2, wr[2 * HIDC + ch], acc[ch]);
        #pragma unroll
        for (int ch = 0; ch < 32; ++ch) acc[ch] = fmaf(v3, wr[3 * HIDC + ch], acc[ch]);
    }
    float dn = dinv[node];
    float4* hr = (float4*)(hs + (size_t)node * HIDC + ch0);
    #pragma unroll
    for (int c4 = 0; c4 < 8; ++c4)
        hr[c4] = make_float4(dn * acc[4 * c4], dn * acc[4 * c4 + 1],
                             dn * acc[4 * c4 + 2], dn * acc[4 * c4 + 3]);
}

// --- gather aggregation: agg[d] = dinv[d] * (hs[d] + sum hs[col]) -------
// 16-wide clamped batches: every batch issues 16 independent row gathers.
__global__ __launch_bounds__(256) void aggregate_csr_kernel(const int* __restrict__ rowptr,
                                                            const unsigned short* __restrict__ col,
                                                            const float* __restrict__ dinv,
                                                            const float* __restrict__ hs,
                                                            float* __restrict__ agg, int N) {
    int node = blockIdx.x * 4 + (threadIdx.x >> 6);
    int lane = threadIdx.x & 63;
    if (node >= N) return;
    float acc = hs[(size_t)node * HIDC + lane];       // self-loop (pre-scaled)
    int j = rowptr[node], end = rowptr[node + 1];
    for (int jb = j; jb < end; jb += 16) {
        int s[16];
        float v[16];
        #pragma unroll
        for (int u = 0; u < 16; ++u) {
            int idx = jb + u;
            s[u] = col[idx < end ? idx : jb];         // clamp -> dup of first (L1 hit)
        }
        #pragma unroll
        for (int u = 0; u < 16; ++u)
            v[u] = hs[(size_t)s[u] * HIDC + lane];
        #pragma unroll
        for (int u = 0; u < 16; ++u)
            acc += (jb + u < end) ? v[u] : 0.f;
    }
    agg[(size_t)node * HIDC + lane] = acc * dinv[node];
}

// --- decode: 16 lanes per edge, float4 ----------------------------------
__global__ __launch_bounds__(256) void decode_kernel(const int* __restrict__ src,
                                                     const int* __restrict__ dst,
                                                     const float* __restrict__ z,
                                                     const float* __restrict__ b2,
                                                     float* __restrict__ out, int E) {
    long long tid = (long long)blockIdx.x * 256 + threadIdx.x;
    int e = (int)(tid >> 4);
    int q = threadIdx.x & 15;
    if (e >= E) return;
    int s = src[e], d = dst[e];
    const float4* z4 = (const float4*)z;
    const float4* b4 = (const float4*)b2;
    float4 bb = b4[q];
    float4 zs = z4[(size_t)s * 16 + q];
    float4 zd = z4[(size_t)d * 16 + q];
    float p = (zs.x + bb.x) * (zd.x + bb.x)
            + (zs.y + bb.y) * (zd.y + bb.y)
            + (zs.z + bb.z) * (zd.z + bb.z)
            + (zs.w + bb.w) * (zd.w + bb.w);
    #pragma unroll
    for (int m = 8; m; m >>= 1) p += __shfl_xor(p, m, 64);
    if (q == 0) out[e] = p;
}

extern "C" void kernel_launch(void* const* d_in, const int* in_sizes, int n_in,
                              void* d_out, int out_size, void* d_ws, size_t ws_size,
                              hipStream_t stream) {
    const float* x  = (const float*)d_in[0];
    const int*   ei = (const int*)d_in[1];
    const float* W1 = (const float*)d_in[2];
    const float* b1 = (const float*)d_in[3];
    const float* W2 = (const float*)d_in[4];
    const float* b2 = (const float*)d_in[5];
    float* out = (float*)d_out;

    const int hid  = in_sizes[3];            // 64
    const int inch = in_sizes[2] / hid;      // 128
    const int N    = in_sizes[0] / inch;     // 50000
    const int E    = in_sizes[1] / 2;        // 800000
    const int* srcp = ei;
    const int* dstp = ei + E;
    int nScanBlocks = (N + 1023) / 1024;

    char* p = (char*)d_ws;
    auto alloc = [&](size_t bytes) { char* r = p; p += (bytes + 255) & ~(size_t)255; return r; };
    int*            count  = (int*)alloc((size_t)(N + 1) * 4);
    int*            rowptr = (int*)alloc((size_t)(N + 1) * 4);
    float*          dinv   = (float*)alloc((size_t)N * 4);
    int*            bsums  = (int*)alloc((size_t)nScanBlocks * 4);
    unsigned short* rank   = (unsigned short*)alloc((size_t)E * 2);
    unsigned short* col    = (unsigned short*)alloc((size_t)E * 2);
    float*          bufA   = (float*)alloc((size_t)N * HIDC * 4);
    float*          bufB   = (float*)alloc((size_t)N * HIDC * 4);

    hipMemsetAsync(count, 0, (size_t)N * 4, stream);

    hist_kernel<<<(E + 255) / 256, 256, 0, stream>>>(dstp, count, rank, E);
    scanA_kernel<<<nScanBlocks, 256, 0, stream>>>(count, rowptr, bsums, N);
    scanB_kernel<<<1, 64, 0, stream>>>(bsums, nScanBlocks);
    scanC_kernel<<<(N + 255) / 256, 256, 0, stream>>>(count, bsums, rowptr, dinv, N, E);
    scatter_kernel<<<(E + 255) / 256, 256, 0, stream>>>(srcp, dstp, rowptr, rank, col, E);

    int gemmGrid = 2 * ((N + 255) / 256);
    gemm1_kernel<<<gemmGrid, 256, 0, stream>>>(x, W1, dinv, bufA, N);              // h1s
    aggregate_csr_kernel<<<(N + 3) / 4, 256, 0, stream>>>(rowptr, col, dinv, bufA, bufB, N);
    gemm2_kernel<<<gemmGrid, 256, 0, stream>>>(bufB, b1, W2, dinv, bufA, N);       // h2s
    aggregate_csr_kernel<<<(N + 3) / 4, 256, 0, stream>>>(rowptr, col, dinv, bufA, bufB, N);

    long long blocksD = ((long long)E * 16 + 255) / 256;
    decode_kernel<<<(int)blocksD, 256, 0, stream>>>(srcp, dstp, bufB, b2, out, E);
}

// Round 6
// 275.455 us; speedup vs baseline: 2.5301x; 1.0154x over previous
//
#include <hip/hip_runtime.h>

// LinkPredictor: 2-layer GCN encode + edge dot decode.
// N=50000, E=800000, IN_CH=128, HID=64.
// R6: fused single-dispatch scan (decoupled lookback), biases folded into
//     aggregate epilogues, 2-edge decode groups, int4 hist/scatter.
#define INCH 128
#define HIDC 64

// --- CSR build ----------------------------------------------------------
__global__ __launch_bounds__(256) void hist_kernel(const int* __restrict__ dst,
                                                   int* __restrict__ count,
                                                   unsigned short* __restrict__ rank, int E) {
    int i4 = (blockIdx.x * 256 + threadIdx.x) * 4;
    if (i4 + 3 < E) {
        int4 d = *(const int4*)(dst + i4);
        ushort4 r;
        r.x = (unsigned short)atomicAdd(&count[d.x], 1);
        r.y = (unsigned short)atomicAdd(&count[d.y], 1);
        r.z = (unsigned short)atomicAdd(&count[d.z], 1);
        r.w = (unsigned short)atomicAdd(&count[d.w], 1);
        *(ushort4*)(rank + i4) = r;
    } else {
        for (int i = i4; i < E; ++i)
            rank[i] = (unsigned short)atomicAdd(&count[dst[i]], 1);
    }
}

// One dispatch: local scan + decoupled-lookback prefix + rowptr/dinv emit.
// state[] must be zeroed before launch (covered by the count memset).
__global__ __launch_bounds__(256) void scan_fused_kernel(const int* __restrict__ count,
                                                         int* __restrict__ state,
                                                         int* __restrict__ rowptr,
                                                         float* __restrict__ dinv,
                                                         int N, int E) {
    int t = threadIdx.x, b = blockIdx.x;
    int base = b * 1024 + t * 4;
    int4 c = make_int4(0, 0, 0, 0);
    if (base + 3 < N) c = *(const int4*)(count + base);
    else {
        if (base + 0 < N) c.x = count[base + 0];
        if (base + 1 < N) c.y = count[base + 1];
        if (base + 2 < N) c.z = count[base + 2];
        if (base + 3 < N) c.w = count[base + 3];
    }
    int tsum = c.x + c.y + c.z + c.w;
    int lane = t & 63, wid = t >> 6;
    int incl = tsum;
    #pragma unroll
    for (int off = 1; off < 64; off <<= 1) {
        int u = __shfl_up(incl, off, 64);
        if (lane >= off) incl += u;
    }
    __shared__ int waveSums[4];
    __shared__ int prefShared;
    if (lane == 63) waveSums[wid] = incl;
    __syncthreads();
    int waveOff = 0;
    for (int w = 0; w < wid; ++w) waveOff += waveSums[w];
    // publish this block's aggregate ASAP (value+1 so nonzero == ready)
    if (t == 0) {
        int blockSum = waveSums[0] + waveSums[1] + waveSums[2] + waveSums[3];
        __hip_atomic_store(&state[b], blockSum + 1, __ATOMIC_RELEASE,
                           __HIP_MEMORY_SCOPE_AGENT);
    }
    // wave 0: poll all predecessor aggregates in parallel, reduce
    if (t < 64) {
        int acc = 0;
        if (lane < b) {
            int v;
            do {
                v = __hip_atomic_load(&state[lane], __ATOMIC_ACQUIRE,
                                      __HIP_MEMORY_SCOPE_AGENT);
            } while (v == 0);
            acc = v - 1;
        }
        #pragma unroll
        for (int m = 32; m; m >>= 1) acc += __shfl_xor(acc, m, 64);
        if (lane == 0) prefShared = acc;
    }
    __syncthreads();
    int texcl = prefShared + waveOff + incl - tsum;
    if (base + 3 < N) {
        *(int4*)(rowptr + base) = make_int4(texcl, texcl + c.x,
                                            texcl + c.x + c.y,
                                            texcl + c.x + c.y + c.z);
        *(float4*)(dinv + base) = make_float4(rsqrtf((float)c.x + 1.f),
                                              rsqrtf((float)c.y + 1.f),
                                              rsqrtf((float)c.z + 1.f),
                                              rsqrtf((float)c.w + 1.f));
    } else {
        int r0 = texcl;
        if (base + 0 < N) { rowptr[base + 0] = r0; dinv[base + 0] = rsqrtf((float)c.x + 1.f); r0 += c.x; }
        if (base + 1 < N) { rowptr[base + 1] = r0; dinv[base + 1] = rsqrtf((float)c.y + 1.f); r0 += c.y; }
        if (base + 2 < N) { rowptr[base + 2] = r0; dinv[base + 2] = rsqrtf((float)c.z + 1.f); r0 += c.z; }
        if (base + 3 < N) { rowptr[base + 3] = r0; dinv[base + 3] = rsqrtf((float)c.w + 1.f); }
    }
    if (b == 0 && t == 0) rowptr[N] = E;
}

__global__ __launch_bounds__(256) void scatter_kernel(const int* __restrict__ src,
                                                      const int* __restrict__ dst,
                                                      const int* __restrict__ rowptr,
                                                      const unsigned short* __restrict__ rank,
                                                      unsigned short* __restrict__ col, int E) {
    int i4 = (blockIdx.x * 256 + threadIdx.x) * 4;
    if (i4 + 3 < E) {
        int4 s = *(const int4*)(src + i4);
        int4 d = *(const int4*)(dst + i4);
        ushort4 r = *(const ushort4*)(rank + i4);
        col[rowptr[d.x] + (int)r.x] = (unsigned short)s.x;
        col[rowptr[d.y] + (int)r.y] = (unsigned short)s.y;
        col[rowptr[d.z] + (int)r.z] = (unsigned short)s.z;
        col[rowptr[d.w] + (int)r.w] = (unsigned short)s.w;
    } else {
        for (int i = i4; i < E; ++i)
            col[rowptr[dst[i]] + (int)rank[i]] = (unsigned short)src[i];
    }
}

// --- dense layers: thread-per-node, W via wave-uniform s_load -----------
__global__ __launch_bounds__(256) void gemm1_kernel(const float* __restrict__ x,
                                                    const float* __restrict__ W,
                                                    const float* __restrict__ dinv,
                                                    float* __restrict__ hs, int N) {
    int node = (blockIdx.x >> 1) * 256 + threadIdx.x;
    int ch0 = (blockIdx.x & 1) * 32;
    if (node >= N) return;
    const float4* xr = (const float4*)(x + (size_t)node * INCH);
    float acc[32];
    #pragma unroll
    for (int c = 0; c < 32; ++c) acc[c] = 0.f;
    for (int kc = 0; kc < INCH / 4; ++kc) {
        float4 xk = xr[kc];
        const float* wr = W + (kc * 4) * HIDC + ch0;
        #pragma unroll
        for (int ch = 0; ch < 32; ++ch) acc[ch] = fmaf(xk.x, wr[ch], acc[ch]);
        #pragma unroll
        for (int ch = 0; ch < 32; ++ch) acc[ch] = fmaf(xk.y, wr[HIDC + ch], acc[ch]);
        #pragma unroll
        for (int ch = 0; ch < 32; ++ch) acc[ch] = fmaf(xk.z, wr[2 * HIDC + ch], acc[ch]);
        #pragma unroll
        for (int ch = 0; ch < 32; ++ch) acc[ch] = fmaf(xk.w, wr[3 * HIDC + ch], acc[ch]);
    }
    float dn = dinv[node];
    float4* hr = (float4*)(hs + (size_t)node * HIDC + ch0);
    #pragma unroll
    for (int c4 = 0; c4 < 8; ++c4)
        hr[c4] = make_float4(dn * acc[4 * c4], dn * acc[4 * c4 + 1],
                             dn * acc[4 * c4 + 2], dn * acc[4 * c4 + 3]);
}

// agg1 already contains +b1; just ReLU at load.
__global__ __launch_bounds__(256) void gemm2_kernel(const float* __restrict__ agg1,
                                                    const float* __restrict__ W,
                                                    const float* __restrict__ dinv,
                                                    float* __restrict__ hs, int N) {
    int node = (blockIdx.x >> 1) * 256 + threadIdx.x;
    int ch0 = (blockIdx.x & 1) * 32;
    if (node >= N) return;
    const float4* ar = (const float4*)(agg1 + (size_t)node * HIDC);
    float acc[32];
    #pragma unroll
    for (int c = 0; c < 32; ++c) acc[c] = 0.f;
    for (int kc = 0; kc < HIDC / 4; ++kc) {
        float4 ak = ar[kc];
        float v0 = fmaxf(ak.x, 0.f);
        float v1 = fmaxf(ak.y, 0.f);
        float v2 = fmaxf(ak.z, 0.f);
        float v3 = fmaxf(ak.w, 0.f);
        const float* wr = W + (kc * 4) * HIDC + ch0;
        #pragma unroll
        for (int ch = 0; ch < 32; ++ch) acc[ch] = fmaf(v0, wr[ch], acc[ch]);
        #pragma unroll
        for (int ch = 0; ch < 32; ++ch) acc[ch] = fmaf(v1, wr[HIDC + ch], acc[ch]);
        #pragma unroll
        for (int ch = 0; ch < 32; ++ch) acc[ch] = fmaf(v2, wr[2 * HIDC + ch], acc[ch]);
        #pragma unroll
        for (int ch = 0; ch < 32; ++ch) acc[ch] = fmaf(v3, wr[3 * HIDC + ch], acc[ch]);
    }
    float dn = dinv[node];
    float4* hr = (float4*)(hs + (size_t)node * HIDC + ch0);
    #pragma unroll
    for (int c4 = 0; c4 < 8; ++c4)
        hr[c4] = make_float4(dn * acc[4 * c4], dn * acc[4 * c4 + 1],
                             dn * acc[4 * c4 + 2], dn * acc[4 * c4 + 3]);
}

// --- gather aggregation: agg[d] = dinv[d]*(hs[d] + sum hs[col]) + bias --
__global__ __launch_bounds__(256) void aggregate_csr_kernel(const int* __restrict__ rowptr,
                                                            const unsigned short* __restrict__ col,
                                                            const float* __restrict__ dinv,
                                                            const float* __restrict__ hs,
                                                            const float* __restrict__ bias,
                                                            float* __restrict__ agg, int N) {
    int node = blockIdx.x * 4 + (threadIdx.x >> 6);
    int lane = threadIdx.x & 63;
    if (node >= N) return;
    float acc = hs[(size_t)node * HIDC + lane];       // self-loop (pre-scaled)
    int j = rowptr[node], end = rowptr[node + 1];
    for (int jb = j; jb < end; jb += 16) {
        int s[16];
        float v[16];
        #pragma unroll
        for (int u = 0; u < 16; ++u) {
            int idx = jb + u;
            s[u] = col[idx < end ? idx : jb];         // clamp -> dup (L1 hit)
        }
        #pragma unroll
        for (int u = 0; u < 16; ++u)
            v[u] = hs[(size_t)s[u] * HIDC + lane];
        #pragma unroll
        for (int u = 0; u < 16; ++u)
            acc += (jb + u < end) ? v[u] : 0.f;
    }
    agg[(size_t)node * HIDC + lane] = fmaf(acc, dinv[node], bias[lane]);
}

// --- decode: 16 lanes per edge, 2 edges per group, z is final -----------
__global__ __launch_bounds__(256) void decode_kernel(const int* __restrict__ src,
                                                     const int* __restrict__ dst,
                                                     const float* __restrict__ z,
                                                     float* __restrict__ out, int E) {
    long long tid = (long long)blockIdx.x * 256 + threadIdx.x;
    int g = (int)(tid >> 4);
    int q = threadIdx.x & 15;
    int e0 = g * 2, e1 = e0 + 1;
    if (e0 >= E) return;
    bool has1 = (e1 < E);
    int s0 = src[e0], d0 = dst[e0];
    int s1 = has1 ? src[e1] : s0;
    int d1 = has1 ? dst[e1] : d0;
    const float4* z4 = (const float4*)z;
    float4 a0 = z4[(size_t)s0 * 16 + q];
    float4 b0 = z4[(size_t)d0 * 16 + q];
    float4 a1 = z4[(size_t)s1 * 16 + q];
    float4 b1 = z4[(size_t)d1 * 16 + q];
    float p0 = a0.x * b0.x + a0.y * b0.y + a0.z * b0.z + a0.w * b0.w;
    float p1 = a1.x * b1.x + a1.y * b1.y + a1.z * b1.z + a1.w * b1.w;
    #pragma unroll
    for (int m = 8; m; m >>= 1) {
        p0 += __shfl_xor(p0, m, 64);
        p1 += __shfl_xor(p1, m, 64);
    }
    if (q == 0) {
        if (has1) *(float2*)(out + e0) = make_float2(p0, p1);
        else out[e0] = p0;
    }
}

extern "C" void kernel_launch(void* const* d_in, const int* in_sizes, int n_in,
                              void* d_out, int out_size, void* d_ws, size_t ws_size,
                              hipStream_t stream) {
    const float* x  = (const float*)d_in[0];
    const int*   ei = (const int*)d_in[1];
    const float* W1 = (const float*)d_in[2];
    const float* b1 = (const float*)d_in[3];
    const float* W2 = (const float*)d_in[4];
    const float* b2 = (const float*)d_in[5];
    float* out = (float*)d_out;

    const int hid  = in_sizes[3];            // 64
    const int inch = in_sizes[2] / hid;      // 128
    const int N    = in_sizes[0] / inch;     // 50000
    const int E    = in_sizes[1] / 2;        // 800000
    const int* srcp = ei;
    const int* dstp = ei + E;
    int nScanBlocks = (N + 1023) / 1024;

    char* p = (char*)d_ws;
    auto alloc = [&](size_t bytes) { char* r = p; p += (bytes + 255) & ~(size_t)255; return r; };
    // count and lookback-state contiguous so one memset zeroes both
    int*            count  = (int*)alloc(((size_t)N + 128) * 4);
    int*            state  = count + N;
    int*            rowptr = (int*)alloc((size_t)(N + 1) * 4);
    float*          dinv   = (float*)alloc((size_t)N * 4);
    unsigned short* rank   = (unsigned short*)alloc((size_t)E * 2);
    unsigned short* col    = (unsigned short*)alloc((size_t)E * 2);
    float*          bufA   = (float*)alloc((size_t)N * HIDC * 4);
    float*          bufB   = (float*)alloc((size_t)N * HIDC * 4);

    hipMemsetAsync(count, 0, ((size_t)N + 128) * 4, stream);

    int histBlocks = (E / 4 + 255) / 256 + 1;
    hist_kernel<<<histBlocks, 256, 0, stream>>>(dstp, count, rank, E);
    scan_fused_kernel<<<nScanBlocks, 256, 0, stream>>>(count, state, rowptr, dinv, N, E);
    scatter_kernel<<<histBlocks, 256, 0, stream>>>(srcp, dstp, rowptr, rank, col, E);

    int gemmGrid = 2 * ((N + 255) / 256);
    gemm1_kernel<<<gemmGrid, 256, 0, stream>>>(x, W1, dinv, bufA, N);              // h1s
    aggregate_csr_kernel<<<(N + 3) / 4, 256, 0, stream>>>(rowptr, col, dinv, bufA, b1, bufB, N);
    gemm2_kernel<<<gemmGrid, 256, 0, stream>>>(bufB, W2, dinv, bufA, N);           // h2s
    aggregate_csr_kernel<<<(N + 3) / 4, 256, 0, stream>>>(rowptr, col, dinv, bufA, b2, bufB, N);

    long long groups = ((long long)E + 1) / 2;
    long long blocksD = (groups * 16 + 255) / 256;
    decode_kernel<<<(int)blocksD, 256, 0, stream>>>(srcp, dstp, bufB, out, E);
}